// Round 3
// baseline (40.693 us; speedup 1.0000x reference)
//
#include <hip/hip_runtime.h>

#define B_SZ 4096
#define IN_D 256
#define OUT_D 256
#define NC 8

#define BM 32
#define BN 64
#define NSTEP 16            // 16 input features (K=128) per step, 16 steps

using f32x4 = __attribute__((ext_vector_type(4))) float;
using s16x8 = __attribute__((ext_vector_type(8))) short;

__device__ __forceinline__ unsigned short f2bf(float f) {
    union { float f; unsigned int u; } v; v.f = f;
    return (unsigned short)((v.u + 0x7fffu + ((v.u >> 16) & 1u)) >> 16);  // RNE
}

__device__ __forceinline__ float fast_tanh(float x) {
    float e = __expf(2.0f * x);   // saturates correctly at +-inf
    return 1.0f - 2.0f / (e + 1.0f);
}

__device__ __forceinline__ void gl2lds16(const void* g, void* l) {
    __builtin_amdgcn_global_load_lds(
        (const __attribute__((address_space(1))) unsigned int*)g,
        (__attribute__((address_space(3))) unsigned int*)l, 16, 0, 0);
}

// ---------------------------------------------------------------------------
// prep_a: A[(i*B + b)*8 + j] = bf16(tanh(x[b,i])^j)   (GEMM-blocked, 16 MB)
// 32b x 64i tile per block; LDS transpose; coalesced read + coalesced write.
// ---------------------------------------------------------------------------
__global__ __launch_bounds__(256) void prep_a(
    const float* __restrict__ x, unsigned short* __restrict__ A)
{
    __shared__ float tt[32][65];
    const int tid = threadIdx.x;
    const int b0 = (blockIdx.x >> 2) * 32;
    const int i0 = (blockIdx.x & 3) * 64;

    #pragma unroll
    for (int it = 0; it < 8; it++) {
        int e = it * 256 + tid;
        int r = e >> 6, c = e & 63;
        tt[r][c] = fast_tanh(x[(size_t)(b0 + r) * IN_D + i0 + c]);
    }
    __syncthreads();

    #pragma unroll
    for (int it = 0; it < 8; it++) {
        int e = it * 256 + tid;
        int ii = e >> 5, bb = e & 31;
        float t = tt[bb][ii];
        unsigned short q[8];
        float p = 1.f;
        #pragma unroll
        for (int j = 0; j < 8; j++) { q[j] = f2bf(p); p *= t; }
        uint4 pk;
        unsigned int* pu = (unsigned int*)&pk;
        #pragma unroll
        for (int h = 0; h < 4; h++)
            pu[h] = (unsigned int)q[2 * h] | ((unsigned int)q[2 * h + 1] << 16);
        *(uint4*)(A + ((size_t)(i0 + ii) * B_SZ + b0 + bb) * 8) = pk;
    }
}

// ---------------------------------------------------------------------------
// prep_w: W[(i*OUT + o)*8 + j] = bf16((1/IN)*(ss[i,o]*sum_c mono[c][j]*cf[i,o,c]
//                                      + (j==1 ? rs[i] : 0)))
// ---------------------------------------------------------------------------
__global__ __launch_bounds__(256) void prep_w(
    const float* __restrict__ coefs, const float* __restrict__ alpha_at,
    const float* __restrict__ resid_scale, const float* __restrict__ spline_scale,
    unsigned short* __restrict__ Wg)
{
    __shared__ float mono[NC][NC];
    const int i = blockIdx.x;
    const int o = threadIdx.x;

    if (o == 0) {
        float al = tanhf(alpha_at[0]);
        float m[NC][NC];
        for (int a = 0; a < NC; a++)
            for (int b = 0; b < NC; b++) m[a][b] = 0.f;
        m[0][0] = 1.f;
        m[1][1] = al + 1.f;
        for (int n = 2; n < NC; n++) {
            float fn = (float)n;
            float c  = 2.f * fn + 2.f * al;
            float An = 2.f * fn * (fn + 2.f * al) * (c - 2.f);
            float Bn = (c - 1.f) * c * (c - 2.f);
            float Cn = 2.f * (fn + al - 1.f) * (fn + al - 1.f) * c;
            for (int j = 0; j < NC; j++) {
                float tm = (j > 0 ? m[n - 1][j - 1] : 0.f);
                m[n][j] = (Bn * tm - Cn * m[n - 2][j]) / An;
            }
        }
        for (int a = 0; a < NC; a++)
            for (int b = 0; b < NC; b++) mono[a][b] = m[a][b];
    }
    __syncthreads();

    float cf[NC];
    const float* cp = coefs + ((size_t)i * OUT_D + o) * NC;
    #pragma unroll
    for (int c = 0; c < NC; c++) cf[c] = cp[c];
    float ss = spline_scale[i * OUT_D + o];
    float rs = resid_scale[i];

    unsigned short w8[NC];
    #pragma unroll
    for (int j = 0; j < NC; j++) {
        float w = 0.f;
        #pragma unroll
        for (int c = 0; c < NC; c++) w += mono[c][j] * cf[c];
        w *= ss * (1.0f / IN_D);
        if (j == 1) w += rs * (1.0f / IN_D);
        w8[j] = f2bf(w);
    }
    uint4 pk;
    unsigned int* pu = (unsigned int*)&pk;
    #pragma unroll
    for (int h = 0; h < 4; h++)
        pu[h] = (unsigned int)w8[2 * h] | ((unsigned int)w8[2 * h + 1] << 16);
    *(uint4*)(Wg + ((size_t)i * OUT_D + o) * NC) = pk;
}

// ---------------------------------------------------------------------------
// GEMM: out[b,o] = sum_k A[k,b]*W[k,o], K=2048. BM=32 x BN=64 exclusive tile,
// BK=128 (16 features), global_load_lds staging, double-buffered, 512 blocks.
// ---------------------------------------------------------------------------
__global__ __launch_bounds__(256) void kan_gemm(
    const unsigned short* __restrict__ A, const unsigned short* __restrict__ Wg,
    float* __restrict__ out)
{
    __shared__ __align__(16) unsigned short At[2][16 * BM * 8];  // 8 KB/buf
    __shared__ __align__(16) unsigned short Wt[2][16 * BN * 8];  // 16 KB/buf

    const int tid  = threadIdx.x;
    const int lane = tid & 63;
    const int w    = tid >> 6;
    const int lr   = lane & 15;
    const int kg   = lane >> 4;

    // XCD-aware bijective swizzle (512 % 8 == 0)
    const int bid  = blockIdx.x;
    const int swz  = (bid & 7) * 64 + (bid >> 3);
    const int mblk = swz >> 2, nblk = swz & 3;
    const int bm = mblk * BM, bn = nblk * BN;

    // Per-lane global source addresses (chunk c = (h*4+w)*64 + lane)
    const unsigned short* ga[2];
    #pragma unroll
    for (int h = 0; h < 2; h++) {
        int c = (h * 4 + w) * 64 + lane;
        int il = c >> 5, m = c & 31;
        ga[h] = A + ((size_t)il * B_SZ + bm + m) * 8;
    }
    const unsigned short* gw[4];
    #pragma unroll
    for (int h = 0; h < 4; h++) {
        int c = (h * 4 + w) * 64 + lane;
        int il = c >> 6, n = c & 63;
        gw[h] = Wg + ((size_t)il * OUT_D + bn + n) * 8;
    }

    f32x4 acc[2];
    acc[0] = (f32x4){0.f, 0.f, 0.f, 0.f};
    acc[1] = (f32x4){0.f, 0.f, 0.f, 0.f};

    auto stage = [&](int buf, int s) {
        const size_t sa = (size_t)s * 16 * B_SZ * 8;   // A step stride (ushorts)
        const size_t sw = (size_t)s * 16 * OUT_D * 8;  // W step stride
        #pragma unroll
        for (int h = 0; h < 2; h++)
            gl2lds16(ga[h] + sa, &At[buf][(h * 4 + w) * 512]);
        #pragma unroll
        for (int h = 0; h < 4; h++)
            gl2lds16(gw[h] + sw, &Wt[buf][(h * 4 + w) * 512]);
    };

    stage(0, 0);
    __syncthreads();

    for (int s = 0; s < NSTEP; ++s) {
        const int cur = s & 1;
        if (s + 1 < NSTEP) stage(cur ^ 1, s + 1);

        s16x8 af[2][4], bfr[4];
        #pragma unroll
        for (int ks = 0; ks < 4; ks++) {
            const int il = ks * 4 + kg;
            bfr[ks]   = *(const s16x8*)(&Wt[cur][(il * BN + w * 16 + lr) * 8]);
            af[0][ks] = *(const s16x8*)(&At[cur][(il * BM + lr) * 8]);
            af[1][ks] = *(const s16x8*)(&At[cur][(il * BM + 16 + lr) * 8]);
        }
        #pragma unroll
        for (int ks = 0; ks < 4; ks++) {
            acc[0] = __builtin_amdgcn_mfma_f32_16x16x32_bf16(af[0][ks], bfr[ks], acc[0], 0, 0, 0);
            acc[1] = __builtin_amdgcn_mfma_f32_16x16x32_bf16(af[1][ks], bfr[ks], acc[1], 0, 0, 0);
        }
        __syncthreads();
    }

    // Epilogue: C/D layout col=lane&15, row=(lane>>4)*4+j; exclusive tile
    #pragma unroll
    for (int f = 0; f < 2; f++)
        #pragma unroll
        for (int j = 0; j < 4; j++) {
            int r = bm + f * 16 + kg * 4 + j;
            int c = bn + w * 16 + lr;
            out[(size_t)r * OUT_D + c] = acc[f][j];
        }
}

extern "C" void kernel_launch(void* const* d_in, const int* in_sizes, int n_in,
                              void* d_out, int out_size, void* d_ws, size_t ws_size,
                              hipStream_t stream) {
    const float* x     = (const float*)d_in[0];
    const float* coefs = (const float*)d_in[1];
    const float* alpha = (const float*)d_in[2];
    const float* rs    = (const float*)d_in[3];
    const float* ss    = (const float*)d_in[4];
    float* out = (float*)d_out;

    unsigned short* Wg = (unsigned short*)d_ws;                      // 1 MB
    unsigned short* Am = (unsigned short*)((char*)d_ws + (1 << 20)); // 16 MB

    prep_a<<<dim3((B_SZ / 32) * (IN_D / 64)), dim3(256), 0, stream>>>(x, Am);
    prep_w<<<dim3(IN_D), dim3(OUT_D), 0, stream>>>(coefs, alpha, rs, ss, Wg);
    kan_gemm<<<dim3((B_SZ / BM) * (OUT_D / BN)), dim3(256), 0, stream>>>(Am, Wg, out);
}

// Round 4
// 25.107 us; speedup vs baseline: 1.6208x; 1.6208x over previous
//
#include <hip/hip_runtime.h>

#define B_SZ 4096
#define IN_D 256
#define OUT_D 256
#define NC 8

#define BM 32
#define BN 64
#define NSTEP 16            // BK=128: 16 input features per step, 16 steps

using f32x4 = __attribute__((ext_vector_type(4))) float;
using s16x8 = __attribute__((ext_vector_type(8))) short;

__device__ __forceinline__ unsigned short f2bf(float f) {
    union { float f; unsigned int u; } v; v.f = f;
    return (unsigned short)((v.u + 0x7fffu + ((v.u >> 16) & 1u)) >> 16);  // RNE
}

__device__ __forceinline__ float fast_tanh(float x) {
    float e = __expf(2.0f * x);   // saturates correctly at +-inf
    return 1.0f - 2.0f / (e + 1.0f);
}

__device__ __forceinline__ void gl2lds16(const void* g, void* l) {
    __builtin_amdgcn_global_load_lds(
        (const __attribute__((address_space(1))) unsigned int*)g,
        (__attribute__((address_space(3))) unsigned int*)l, 16, 0, 0);
}

// ---------------------------------------------------------------------------
// prep_w: W[(i*OUT + o)*8 + j] = bf16((1/IN)*(ss[i,o]*sum_c mono[c][j]*cf[c]
//                                     + (j==1 ? rs[i] : 0)))
// mono computed redundantly per-thread (all static-indexed, no LDS/serial).
// ---------------------------------------------------------------------------
__global__ __launch_bounds__(256) void prep_w(
    const float* __restrict__ coefs, const float* __restrict__ alpha_at,
    const float* __restrict__ resid_scale, const float* __restrict__ spline_scale,
    unsigned short* __restrict__ Wg)
{
    const int i = blockIdx.x;
    const int o = threadIdx.x;

    float al = tanhf(alpha_at[0]);
    float mono[NC][NC];
    #pragma unroll
    for (int a = 0; a < NC; a++)
        #pragma unroll
        for (int b = 0; b < NC; b++) mono[a][b] = 0.f;
    mono[0][0] = 1.f;
    mono[1][1] = al + 1.f;
    #pragma unroll
    for (int n = 2; n < NC; n++) {
        float fn = (float)n;
        float c  = 2.f * fn + 2.f * al;
        float An = 2.f * fn * (fn + 2.f * al) * (c - 2.f);
        float Bn = (c - 1.f) * c * (c - 2.f);
        float Cn = 2.f * (fn + al - 1.f) * (fn + al - 1.f) * c;
        #pragma unroll
        for (int j = 0; j < NC; j++) {
            float tm = (j > 0 ? mono[n - 1][j - 1] : 0.f);
            mono[n][j] = (Bn * tm - Cn * mono[n - 2][j]) / An;
        }
    }

    float cf[NC];
    const float* cp = coefs + ((size_t)i * OUT_D + o) * NC;
    #pragma unroll
    for (int c = 0; c < NC; c++) cf[c] = cp[c];
    float ss = spline_scale[i * OUT_D + o];
    float rs = resid_scale[i];

    unsigned short w8[NC];
    #pragma unroll
    for (int j = 0; j < NC; j++) {
        float wv = 0.f;
        #pragma unroll
        for (int c = 0; c < NC; c++) wv += mono[c][j] * cf[c];
        wv *= ss * (1.0f / IN_D);
        if (j == 1) wv += rs * (1.0f / IN_D);
        w8[j] = f2bf(wv);
    }
    uint4 pk;
    unsigned int* pu = (unsigned int*)&pk;
    #pragma unroll
    for (int h = 0; h < 4; h++)
        pu[h] = (unsigned int)w8[2 * h] | ((unsigned int)w8[2 * h + 1] << 16);
    *(uint4*)(Wg + ((size_t)i * OUT_D + o) * NC) = pk;
}

// ---------------------------------------------------------------------------
// Fused GEMM: out[b,o] = sum_{i,j} t[b,i]^j * W[i*8+j, o],  t = tanh(x).
// t kept in registers (32/thread, loaded once); A-tile generated cooperatively
// into dbuf LDS each step; W staged via global_load_lds. BM=32 x BN=64,
// BK=128, 16 steps, 512 blocks (2/CU), 256 threads. Fully unrolled K-loop.
// ---------------------------------------------------------------------------
__global__ __launch_bounds__(256) void kan_gemm(
    const float* __restrict__ x, const unsigned short* __restrict__ Wg,
    float* __restrict__ out)
{
    __shared__ __align__(16) unsigned short Wt[2][16 * BN * 8];  // 2 x 16 KB
    __shared__ __align__(16) unsigned short At[2][16 * BM * 8];  // 2 x 8 KB

    const int tid  = threadIdx.x;
    const int lane = tid & 63;
    const int w    = tid >> 6;
    const int lr   = lane & 15;
    const int kg   = lane >> 4;

    // XCD-aware bijective swizzle (512 % 8 == 0)
    const int bid  = blockIdx.x;
    const int swz  = (bid & 7) * 64 + (bid >> 3);
    const int mblk = swz >> 2, nblk = swz & 3;
    const int bm = mblk * BM, bn = nblk * BN;

    // t in registers: this thread owns rows m_, features il = 2*u_ + z (per step)
    const int m_ = tid & 31, u_ = tid >> 5;
    float treg[2][NSTEP];
    {
        const float* xrow = x + (size_t)(bm + m_) * IN_D + 2 * u_;
        #pragma unroll
        for (int s = 0; s < NSTEP; s++) {
            treg[0][s] = fast_tanh(xrow[s * 16]);
            treg[1][s] = fast_tanh(xrow[s * 16 + 1]);
        }
    }

    f32x4 acc[2];
    acc[0] = (f32x4){0.f, 0.f, 0.f, 0.f};
    acc[1] = (f32x4){0.f, 0.f, 0.f, 0.f};

    auto stage = [&](int buf, int s) {
        // W tile: 1024 x 16B chunks, 4/thread, contiguous 1KB per instr
        const unsigned short* wbase = Wg + ((size_t)(s * 16) * OUT_D + bn) * 8;
        #pragma unroll
        for (int h = 0; h < 4; h++) {
            int c  = h * 256 + tid;
            int il = c >> 6;          // = h*4 + w (wave-uniform)
            gl2lds16(wbase + ((size_t)il * OUT_D + (c & 63)) * 8, &Wt[buf][c * 8]);
        }
        // A tile: 2 power-chains per thread from registers
        #pragma unroll
        for (int z = 0; z < 2; z++) {
            float t = treg[z][s];
            unsigned short q[8];
            float p = 1.f;
            #pragma unroll
            for (int j = 0; j < 8; j++) { q[j] = f2bf(p); p *= t; }
            uint4 pk;
            unsigned int* pu = (unsigned int*)&pk;
            #pragma unroll
            for (int h2 = 0; h2 < 4; h2++)
                pu[h2] = (unsigned int)q[2 * h2] | ((unsigned int)q[2 * h2 + 1] << 16);
            *(uint4*)(&At[buf][((2 * u_ + z) * BM + m_) * 8]) = pk;
        }
    };

    stage(0, 0);
    __syncthreads();

    #pragma unroll
    for (int s = 0; s < NSTEP; ++s) {
        const int cur = s & 1;
        if (s + 1 < NSTEP) stage(cur ^ 1, s + 1);

        s16x8 af[2][4], bfr[4];
        #pragma unroll
        for (int ks = 0; ks < 4; ks++) {
            const int il = ks * 4 + kg;
            bfr[ks]   = *(const s16x8*)(&Wt[cur][(il * BN + w * 16 + lr) * 8]);
            af[0][ks] = *(const s16x8*)(&At[cur][(il * BM + lr) * 8]);
            af[1][ks] = *(const s16x8*)(&At[cur][(il * BM + 16 + lr) * 8]);
        }
        #pragma unroll
        for (int ks = 0; ks < 4; ks++) {
            acc[0] = __builtin_amdgcn_mfma_f32_16x16x32_bf16(af[0][ks], bfr[ks], acc[0], 0, 0, 0);
            acc[1] = __builtin_amdgcn_mfma_f32_16x16x32_bf16(af[1][ks], bfr[ks], acc[1], 0, 0, 0);
        }
        __syncthreads();
    }

    // Epilogue: C/D layout col=lane&15, row=(lane>>4)*4+j; exclusive tile
    #pragma unroll
    for (int f = 0; f < 2; f++)
        #pragma unroll
        for (int j = 0; j < 4; j++) {
            int r = bm + f * 16 + kg * 4 + j;
            int c = bn + w * 16 + lr;
            out[(size_t)r * OUT_D + c] = acc[f][j];
        }
}

extern "C" void kernel_launch(void* const* d_in, const int* in_sizes, int n_in,
                              void* d_out, int out_size, void* d_ws, size_t ws_size,
                              hipStream_t stream) {
    const float* x     = (const float*)d_in[0];
    const float* coefs = (const float*)d_in[1];
    const float* alpha = (const float*)d_in[2];
    const float* rs    = (const float*)d_in[3];
    const float* ss    = (const float*)d_in[4];
    float* out = (float*)d_out;
    unsigned short* Wg = (unsigned short*)d_ws;   // 1 MB

    prep_w<<<dim3(IN_D), dim3(OUT_D), 0, stream>>>(coefs, alpha, rs, ss, Wg);
    kan_gemm<<<dim3((B_SZ / BM) * (OUT_D / BN)), dim3(256), 0, stream>>>(x, Wg, out);
}